// Round 1
// baseline (33.240 us; speedup 1.0000x reference)
//
#include <hip/hip_runtime.h>

// Problem constants (match reference)
#define BATCH 4
#define QLEN 2048
#define CLEN 2048
#define DIM 512
#define NCH 64                 // context row-chunks per batch for stage-1 reduce
#define RPC (CLEN / NCH)       // 32 rows per chunk

// The whole reference collapses: einsum 'bqkh,bvha->bqha' has independent k and v,
// and softmax over k sums to exactly 1, so
//   out[b,q,:] = ((sum_cl context[b,cl,:]) @ Wkv[:,D:2D]) @ Wout   for every q.
// query, Wq, mask are dead inputs.

// ---- Stage 1: partial column sums of context: partial[b][ch][d] ----
__global__ __launch_bounds__(512) void k_csum_partial(const float* __restrict__ ctx,
                                                      float* __restrict__ partial) {
    __shared__ float4 red[512];
    const int blk = blockIdx.x;        // b*NCH + ch
    const int b   = blk >> 6;          // /NCH
    const int ch  = blk & (NCH - 1);
    const int t   = threadIdx.x;
    const int rg  = t >> 7;            // row group 0..3
    const int f4  = t & 127;           // float4 column index
    const float4* p =
        reinterpret_cast<const float4*>(ctx + ((size_t)(b * CLEN + ch * RPC + rg)) * DIM) + f4;
    float4 s = make_float4(0.f, 0.f, 0.f, 0.f);
#pragma unroll
    for (int r = 0; r < RPC / 4; ++r) {
        float4 x = p[(size_t)r * 4 * (DIM / 4)];
        s.x += x.x; s.y += x.y; s.z += x.z; s.w += x.w;
    }
    red[t] = s;
    __syncthreads();
    if (t < 128) {
        float4 a = red[t], b4 = red[t + 128], c = red[t + 256], d4 = red[t + 384];
        float4 o = make_float4(a.x + b4.x + c.x + d4.x, a.y + b4.y + c.y + d4.y,
                               a.z + b4.z + c.z + d4.z, a.w + b4.w + c.w + d4.w);
        reinterpret_cast<float4*>(partial)[blk * (DIM / 4) + t] = o;
    }
}

// ---- Stage 2: reduce partials -> csum[b][d] ----
__global__ __launch_bounds__(256) void k_csum_reduce(const float* __restrict__ partial,
                                                     float* __restrict__ csum) {
    const int i = blockIdx.x * 256 + threadIdx.x;  // 0..BATCH*DIM-1
    const int b = i >> 9;
    const int d = i & (DIM - 1);
    const float* p = partial + (size_t)b * NCH * DIM + d;
    float s = 0.f;
#pragma unroll 8
    for (int ch = 0; ch < NCH; ++ch) s += p[ch * DIM];
    csum[i] = s;
}

// ---- Stage 3: vpart[ks][b][e] = sum_{d in slice ks} csum[b][d] * Wkv[d][512+e] ----
// grid 32 = (ks 0..3) x (e-chunk 0..7); 256 threads = (b 0..3) x (e_local 0..63)
__global__ __launch_bounds__(256) void k_vsum_part(const float* __restrict__ csum,
                                                   const float* __restrict__ Wkv,
                                                   float* __restrict__ vpart) {
    __shared__ float cs[BATCH][128];
    const int ks = blockIdx.x >> 3;
    const int ec = blockIdx.x & 7;
    const int t  = threadIdx.x;
    const int b  = t >> 6;             // whole wave shares one b -> LDS broadcast
    const int el = t & 63;
    const int e  = ec * 64 + el;
    for (int j = t; j < BATCH * 128; j += 256) {
        int bb = j >> 7, dd = j & 127;
        cs[bb][dd] = csum[bb * DIM + ks * 128 + dd];
    }
    __syncthreads();
    const float* w = Wkv + (size_t)(ks * 128) * (2 * DIM) + DIM + e;
    float s = 0.f;
#pragma unroll 8
    for (int d0 = 0; d0 < 128; ++d0) s += cs[b][d0] * w[(size_t)d0 * (2 * DIM)];
    vpart[(ks * BATCH + b) * DIM + e] = s;
}

// ---- Stage 4: opart[ks][b][f] = sum_{e in slice ks} vsum[b][e] * Wout[e][f] ----
__global__ __launch_bounds__(256) void k_orow_part(const float* __restrict__ vpart,
                                                   const float* __restrict__ Wout,
                                                   float* __restrict__ opart) {
    __shared__ float vs[BATCH][128];
    const int ks = blockIdx.x >> 3;
    const int fc = blockIdx.x & 7;
    const int t  = threadIdx.x;
    const int b  = t >> 6;
    const int fl = t & 63;
    const int f  = fc * 64 + fl;
    for (int j = t; j < BATCH * 128; j += 256) {
        int bb = j >> 7, ee = j & 127;
        int idx = bb * DIM + ks * 128 + ee;
        vs[bb][ee] = vpart[idx] + vpart[BATCH * DIM + idx] +
                     vpart[2 * BATCH * DIM + idx] + vpart[3 * BATCH * DIM + idx];
    }
    __syncthreads();
    const float* w = Wout + (size_t)(ks * 128) * DIM + f;
    float s = 0.f;
#pragma unroll 8
    for (int e0 = 0; e0 < 128; ++e0) s += vs[b][e0] * w[(size_t)e0 * DIM];
    opart[(ks * BATCH + b) * DIM + f] = s;
}

// ---- Stage 5: out[b,q,:] = sum_ks opart[ks][b][:]  (row broadcast over q) ----
__global__ __launch_bounds__(256) void k_broadcast(const float* __restrict__ opart,
                                                   float4* __restrict__ out) {
    const int total4 = BATCH * QLEN * (DIM / 4);  // 1<<20
    const float4* op = reinterpret_cast<const float4*>(opart);
    int i = blockIdx.x * 256 + threadIdx.x;
    const int stride = gridDim.x * 256;
    for (; i < total4; i += stride) {
        const int b    = i >> 18;       // QLEN*(DIM/4) = 2^18 float4 per batch
        const int f4   = i & 127;
        const int base = b * 128 + f4;  // opart float4 index for ks=0
        float4 a  = op[base];
        float4 b4 = op[base + 512];
        float4 c  = op[base + 1024];
        float4 d4 = op[base + 1536];
        out[i] = make_float4(a.x + b4.x + c.x + d4.x, a.y + b4.y + c.y + d4.y,
                             a.z + b4.z + c.z + d4.z, a.w + b4.w + c.w + d4.w);
    }
}

extern "C" void kernel_launch(void* const* d_in, const int* in_sizes, int n_in,
                              void* d_out, int out_size, void* d_ws, size_t ws_size,
                              hipStream_t stream) {
    // inputs: 0=query (unused), 1=context, 2=mask (unused), 3=Wq (unused), 4=Wkv, 5=Wout
    const float* ctx  = (const float*)d_in[1];
    const float* Wkv  = (const float*)d_in[4];
    const float* Wout = (const float*)d_in[5];
    float* ws = (float*)d_ws;
    float* partial = ws;                                 // BATCH*NCH*DIM   = 131072 f
    float* csum    = partial + BATCH * NCH * DIM;        // BATCH*DIM      = 2048 f
    float* vpart   = csum + BATCH * DIM;                 // 4*BATCH*DIM    = 8192 f
    float* opart   = vpart + 4 * BATCH * DIM;            // 4*BATCH*DIM    = 8192 f

    k_csum_partial<<<BATCH * NCH, 512, 0, stream>>>(ctx, partial);
    k_csum_reduce<<<8, 256, 0, stream>>>(partial, csum);
    k_vsum_part<<<32, 256, 0, stream>>>(csum, Wkv, vpart);
    k_orow_part<<<32, 256, 0, stream>>>(vpart, Wout, opart);
    k_broadcast<<<2048, 256, 0, stream>>>(opart, (float4*)d_out);
}

// Round 2
// 32.941 us; speedup vs baseline: 1.0091x; 1.0091x over previous
//
#include <hip/hip_runtime.h>

// Problem constants (match reference)
#define BATCH 4
#define QLEN 2048
#define CLEN 2048
#define DIM 512
#define NCH 64                 // context row-chunks per batch for stage-1 reduce
#define RPC (CLEN / NCH)       // 32 rows per chunk

// The whole reference collapses: einsum 'bqkh,bvha->bqha' has independent k and v,
// and softmax over k sums to exactly 1, so
//   out[b,q,:] = ((sum_cl context[b,cl,:]) @ Wkv[:,D:2D]) @ Wout   for every q.
// query, Wq, mask are dead inputs.
//
// 3-kernel chain (was 5): csum-partial -> fused(reduce+vsum) -> fused(orow+broadcast)

// ---- K1: partial column sums of context: partial[b][ch][d] ----
__global__ __launch_bounds__(512) void k_csum_partial(const float* __restrict__ ctx,
                                                      float* __restrict__ partial) {
    __shared__ float4 red[512];
    const int blk = blockIdx.x;        // b*NCH + ch
    const int b   = blk >> 6;          // /NCH
    const int ch  = blk & (NCH - 1);
    const int t   = threadIdx.x;
    const int rg  = t >> 7;            // row group 0..3
    const int f4  = t & 127;           // float4 column index
    const float4* p =
        reinterpret_cast<const float4*>(ctx + ((size_t)(b * CLEN + ch * RPC + rg)) * DIM) + f4;
    float4 s = make_float4(0.f, 0.f, 0.f, 0.f);
#pragma unroll
    for (int r = 0; r < RPC / 4; ++r) {
        float4 x = p[(size_t)r * 4 * (DIM / 4)];
        s.x += x.x; s.y += x.y; s.z += x.z; s.w += x.w;
    }
    red[t] = s;
    __syncthreads();
    if (t < 128) {
        float4 a = red[t], b4 = red[t + 128], c = red[t + 256], d4 = red[t + 384];
        float4 o = make_float4(a.x + b4.x + c.x + d4.x, a.y + b4.y + c.y + d4.y,
                               a.z + b4.z + c.z + d4.z, a.w + b4.w + c.w + d4.w);
        reinterpret_cast<float4*>(partial)[blk * (DIM / 4) + t] = o;
    }
}

// ---- K2: fused partial-reduce + V matvec slice ----
// grid 32 = (ks 0..3) x (ec 0..7); 256 threads
// vpart[ks][b][e] = sum_{d in slice ks} csum[b][d] * Wkv[d][512+e]
__global__ __launch_bounds__(256) void k_reduce_vsum(const float* __restrict__ partial,
                                                     const float* __restrict__ Wkv,
                                                     float* __restrict__ vpart) {
    __shared__ float cs[BATCH][128];
    const int ks = blockIdx.x >> 3;
    const int ec = blockIdx.x & 7;
    const int t  = threadIdx.x;
    // reduce the 4x128 csum slice this block needs (reads 32KB, L2-hot)
    for (int j = t; j < BATCH * 128; j += 256) {
        const int bb = j >> 7, dd = j & 127;
        const float* p = partial + (size_t)bb * NCH * DIM + ks * 128 + dd;
        float s = 0.f;
#pragma unroll 8
        for (int ch = 0; ch < NCH; ++ch) s += p[ch * DIM];
        cs[bb][dd] = s;
    }
    __syncthreads();
    const int b  = t >> 6;             // whole wave shares one b -> LDS broadcast
    const int el = t & 63;
    const int e  = ec * 64 + el;
    const float* w = Wkv + (size_t)(ks * 128) * (2 * DIM) + DIM + e;
    float s = 0.f;
#pragma unroll 8
    for (int d0 = 0; d0 < 128; ++d0) s += cs[b][d0] * w[(size_t)d0 * (2 * DIM)];
    vpart[(ks * BATCH + b) * DIM + e] = s;
}

// ---- K3: fused vsum-combine + out-row matvec + broadcast ----
// grid 512 = b(4) x fc(8) x qc(16); 256 threads
__global__ __launch_bounds__(256) void k_orow_bcast(const float* __restrict__ vpart,
                                                    const float* __restrict__ Wout,
                                                    float4* __restrict__ out) {
    __shared__ float vs[DIM];
    __shared__ float red[256];
    __shared__ float orow[64];
    const int blk = blockIdx.x;
    const int qc  = blk & 15;
    const int fc  = (blk >> 4) & 7;
    const int b   = blk >> 7;
    const int t   = threadIdx.x;
    // vsum[b][:] = sum over ks of vpart slices (8KB, L2-hot)
    for (int j = t; j < DIM; j += 256) {
        const int idx = b * DIM + j;
        vs[j] = vpart[idx] + vpart[BATCH * DIM + idx] +
                vpart[2 * BATCH * DIM + idx] + vpart[3 * BATCH * DIM + idx];
    }
    __syncthreads();
    // orow[fl] for f = fc*64+fl; thread = (eq 0..3) x (fl 0..63), partial over 128 e's
    const int fl = t & 63, eq = t >> 6;
    const float* w = Wout + (size_t)(eq * 128) * DIM + fc * 64 + fl;
    float s = 0.f;
#pragma unroll 8
    for (int e0 = 0; e0 < 128; ++e0) s += vs[eq * 128 + e0] * w[(size_t)e0 * DIM];
    red[t] = s;
    __syncthreads();
    if (t < 64) orow[t] = red[t] + red[64 + t] + red[128 + t] + red[192 + t];
    __syncthreads();
    // broadcast rows q = qc*128 .. +127, cols f = fc*64 .. +63 (16 float4 per row)
    const float4 val = reinterpret_cast<const float4*>(orow)[t & 15];
    float4* dst = out + ((size_t)(b * QLEN) + qc * 128 + (t >> 4)) * (DIM / 4)
                      + fc * 16 + (t & 15);
#pragma unroll
    for (int i = 0; i < 8; ++i) dst[(size_t)i * 16 * (DIM / 4)] = val;
}

extern "C" void kernel_launch(void* const* d_in, const int* in_sizes, int n_in,
                              void* d_out, int out_size, void* d_ws, size_t ws_size,
                              hipStream_t stream) {
    // inputs: 0=query (unused), 1=context, 2=mask (unused), 3=Wq (unused), 4=Wkv, 5=Wout
    const float* ctx  = (const float*)d_in[1];
    const float* Wkv  = (const float*)d_in[4];
    const float* Wout = (const float*)d_in[5];
    float* ws = (float*)d_ws;
    float* partial = ws;                                 // BATCH*NCH*DIM = 131072 f
    float* vpart   = partial + BATCH * NCH * DIM;        // 4*BATCH*DIM  = 8192 f

    k_csum_partial<<<BATCH * NCH, 512, 0, stream>>>(ctx, partial);
    k_reduce_vsum<<<32, 256, 0, stream>>>(partial, Wkv, vpart);
    k_orow_bcast<<<512, 256, 0, stream>>>(vpart, Wout, (float4*)d_out);
}